// Round 4
// baseline (425.535 us; speedup 1.0000x reference)
//
#include <hip/hip_runtime.h>

// AlphaGridMask: normalize coords (+ inf-norm contract), trilinear sample of
// 256^3 volume (align_corners=True, zero pad).
//
// R9b: two-phase u16-pair table (R6 structure) + KPT=8 MLP batching (R8's fix).
// (R9 resubmit: round-3 bench was an infra failure, kernel never ran. Only
// change: removed the __launch_bounds__ min-waves hint -- with KPT=8 live
// state it over-constrains the register allocator and risks scratch spill.)
// Evidence so far:
//   R6: 2-phase, ~4.3MB/phase working set, 2 loads/pt, KPT=1 -> L2-resident
//       but latency-bound (81us/phase, occ 75% with only ~2 misses/wave).
//   R7: 1-pass 4MB u8 table, 8 byte-transactions/pt -> transaction-bound (176us).
//   R8: 1-pass 33MB 8B-entry table, 1 load/pt -> NOT cache-resident (FETCH
//       522MB, 66% miss/pt) + occ 21% -> latency/fill-bound (170us).
// Conclusion: working set must be <= ~4MB (per-XCD L2), transactions/pt must
// stay at 2, and each thread must keep ~16 scattered loads in flight.
// This kernel: phase 0 = inside points (dist<=1), phase 1 = shell. Each
// phase's table slice (~4.3MB) stays L2-resident; KPT=8 hides L2-hit latency.

#define DD 256
#define HH 256
#define WW 256

#define R0   47                       // min accessed corner index
#define XE   162                      // x entries: 47..208
#define YE   161                      // y-pair bases: 47..207 (pair = y,y+1)
#define ZE   162                      // z entries: 47..208
#define QENT (XE * YE * ZE)
#define QBYTES ((size_t)QENT * 2)     // 8,449,128 bytes

#define KPT 8                         // points per thread (MLP batching)

typedef float fvec4 __attribute__((ext_vector_type(4)));
typedef unsigned int u32a2 __attribute__((aligned(2)));

__device__ __forceinline__ unsigned int quant_u8(float v) {
    return (unsigned int)(fminf(fmaxf(v, 0.f), 1.f) * 255.0f + 0.5f);
}

// QT[((z-47)*YE + (yb-47))*XE + (x-47)] = q(vol[z][yb][x]) | q(vol[z][yb+1][x])<<8
__global__ __launch_bounds__(256) void build_qt_kernel(
    const float* __restrict__ vol,
    unsigned short* __restrict__ qt)
{
    int i = blockIdx.x * blockDim.x + threadIdx.x;
    if (i >= QENT) return;
    int x  = i % XE;
    int t  = i / XE;
    int yb = t % YE;
    int z  = t / YE;
    size_t base = ((size_t)(z + R0) << 16) | ((yb + R0) << 8) | (x + R0);
    float v0 = __builtin_nontemporal_load(vol + base);
    float v1 = __builtin_nontemporal_load(vol + base + WW);   // y+1 row
    qt[i] = (unsigned short)(quant_u8(v0) | (quant_u8(v1) << 8));
}

// exact f32 trilinear with zero-padding masks (cold path / fallback)
__device__ __forceinline__ float slow_sample(const float* __restrict__ vol,
                                             float cx, float cy, float cz)
{
    float ix = (cx + 1.0f) * 0.5f * (float)(WW - 1);
    float iy = (cy + 1.0f) * 0.5f * (float)(HH - 1);
    float iz = (cz + 1.0f) * 0.5f * (float)(DD - 1);

    float x0f = floorf(ix), y0f = floorf(iy), z0f = floorf(iz);
    float tx = ix - x0f, ty = iy - y0f, tz = iz - z0f;
    int x0 = (int)x0f, y0 = (int)y0f, z0 = (int)z0f;
    int x1 = x0 + 1,   y1 = y0 + 1,   z1 = z0 + 1;

    float mx0 = ((unsigned)x0 < (unsigned)WW) ? 1.0f : 0.0f;
    float mx1 = ((unsigned)x1 < (unsigned)WW) ? 1.0f : 0.0f;
    float my0 = ((unsigned)y0 < (unsigned)HH) ? 1.0f : 0.0f;
    float my1 = ((unsigned)y1 < (unsigned)HH) ? 1.0f : 0.0f;
    float mz0 = ((unsigned)z0 < (unsigned)DD) ? 1.0f : 0.0f;
    float mz1 = ((unsigned)z1 < (unsigned)DD) ? 1.0f : 0.0f;

    int xc0 = min(max(x0, 0), WW - 1), xc1 = min(max(x1, 0), WW - 1);
    int yc0 = min(max(y0, 0), HH - 1), yc1 = min(max(y1, 0), HH - 1);
    int zc0 = min(max(z0, 0), DD - 1), zc1 = min(max(z1, 0), DD - 1);

    float wx0 = (1.0f - tx) * mx0, wx1 = tx * mx1;
    float wy0 = (1.0f - ty) * my0, wy1 = ty * my1;
    float wz0 = (1.0f - tz) * mz0, wz1 = tz * mz1;

    const float* vz0y0 = vol + (((size_t)zc0 * HH + yc0) * WW);
    const float* vz0y1 = vol + (((size_t)zc0 * HH + yc1) * WW);
    const float* vz1y0 = vol + (((size_t)zc1 * HH + yc0) * WW);
    const float* vz1y1 = vol + (((size_t)zc1 * HH + yc1) * WW);

    return wz0 * (wy0 * (wx0 * vz0y0[xc0] + wx1 * vz0y0[xc1]) +
                  wy1 * (wx0 * vz0y1[xc0] + wx1 * vz0y1[xc1])) +
           wz1 * (wy0 * (wx0 * vz1y0[xc0] + wx1 * vz1y0[xc1]) +
                  wy1 * (wx0 * vz1y1[xc0] + wx1 * vz1y1[xc1]));
}

// phase 0: inside points (dist<=1, and everything when contract==0); phase 1: shell
// ca[k] semantics: >=0 fast table index; -1 not-my-phase/oob-i; -2 my phase, slow path
__global__ __launch_bounds__(256) void sample_phase_kernel(
    const float* __restrict__ xyz,            // [N*4]
    const unsigned short* __restrict__ qt,
    const float* __restrict__ vol,            // slow-path fallback only
    const float* __restrict__ aabb,
    const int* __restrict__ contract,
    float* __restrict__ out,
    int n, int phase)
{
    int i0 = blockIdx.x * (256 * KPT) + threadIdx.x;

    const float amin_x = aabb[0], amin_y = aabb[1], amin_z = aabb[2];
    const float amax_x = aabb[3], amax_y = aabb[4], amax_z = aabb[5];
    const float gx = 2.0f / (amax_x - amin_x);
    const float gy = 2.0f / (amax_y - amin_y);
    const float gz = 2.0f / (amax_z - amin_z);
    const int ct = *contract;

    // ---- stage 1: issue all K xyz loads (independent, NT, coalesced) ----
    fvec4 p[KPT];
    #pragma unroll
    for (int k = 0; k < KPT; k++) {
        int i = i0 + k * 256;
        if (i < n) p[k] = __builtin_nontemporal_load((const fvec4*)xyz + i);
        else       p[k] = (fvec4)(0.0f);
    }

    // ---- stage 2: coords -> phase mask, table index, lerp weights ----
    int   ca[KPT];
    float tx[KPT], ty[KPT], tz[KPT];
    #pragma unroll
    for (int k = 0; k < KPT; k++) {
        int i = i0 + k * 256;
        float cx = (p[k].x - amin_x) * gx - 1.0f;
        float cy = (p[k].y - amin_y) * gy - 1.0f;
        float cz = (p[k].z - amin_z) * gz - 1.0f;
        bool outside = false;
        if (ct) {
            float dist = fmaxf(fabsf(cx), fmaxf(fabsf(cy), fabsf(cz))) + 1e-8f;
            outside = (dist > 1.0f);
            float val  = outside ? (2.0f - 1.0f / dist) : dist;
            float s    = val * 0.5f / dist;
            cx *= s; cy *= s; cz *= s;
        }
        bool mine = (i < n) && (outside == (phase != 0));

        float ix = (cx + 1.0f) * 0.5f * (float)(WW - 1);
        float iy = (cy + 1.0f) * 0.5f * (float)(HH - 1);
        float iz = (cz + 1.0f) * 0.5f * (float)(DD - 1);
        float x0f = floorf(ix), y0f = floorf(iy), z0f = floorf(iz);
        tx[k] = ix - x0f; ty[k] = iy - y0f; tz[k] = iz - z0f;
        int x0 = (int)x0f, y0 = (int)y0f, z0 = (int)z0f;

        bool fast = ((unsigned)(x0 - R0) <= (unsigned)(XE - 2)) &
                    ((unsigned)(y0 - R0) <= (unsigned)(YE - 1)) &
                    ((unsigned)(z0 - R0) <= (unsigned)(ZE - 2));
        int idx = ((z0 - R0) * YE + (y0 - R0)) * XE + (x0 - R0);
        ca[k] = mine ? (fast ? idx : -2) : -1;
    }

    // ---- stage 3: issue all scattered table loads together (MLP) ----
    unsigned int L0[KPT], L1[KPT];
    #pragma unroll
    for (int k = 0; k < KPT; k++) {
        if (ca[k] >= 0) {
            L0[k] = *(const u32a2*)(qt + ca[k]);
            L1[k] = *(const u32a2*)(qt + ca[k] + YE * XE);
        } else {
            L0[k] = L1[k] = 0u;
        }
    }

    // ---- stage 4: trilinear combine + NT store ----
    #pragma unroll
    for (int k = 0; k < KPT; k++) {
        if (ca[k] == -1) continue;
        int i = i0 + k * 256;
        float r;
        if (__builtin_expect(ca[k] >= 0, 1)) {
            float v000 = (float)( L0[k]        & 0xFFu);
            float v010 = (float)((L0[k] >>  8) & 0xFFu);
            float v001 = (float)((L0[k] >> 16) & 0xFFu);
            float v011 = (float)( L0[k] >> 24);
            float v100 = (float)( L1[k]        & 0xFFu);
            float v110 = (float)((L1[k] >>  8) & 0xFFu);
            float v101 = (float)((L1[k] >> 16) & 0xFFu);
            float v111 = (float)( L1[k] >> 24);

            float wx0 = 1.0f - tx[k], wx1 = tx[k];
            float wy0 = 1.0f - ty[k], wy1 = ty[k];
            float wz0 = 1.0f - tz[k], wz1 = tz[k];

            r = (wz0 * (wy0 * (wx0 * v000 + wx1 * v001) +
                        wy1 * (wx0 * v010 + wx1 * v011)) +
                 wz1 * (wy0 * (wx0 * v100 + wx1 * v101) +
                        wy1 * (wx0 * v110 + wx1 * v111))) * (1.0f / 255.0f);
        } else {
            // cold path: recompute coords from a reload (keeps hot regs lean)
            fvec4 q = *((const fvec4*)xyz + i);
            float cx = (q.x - amin_x) * gx - 1.0f;
            float cy = (q.y - amin_y) * gy - 1.0f;
            float cz = (q.z - amin_z) * gz - 1.0f;
            if (ct) {
                float dist = fmaxf(fabsf(cx), fmaxf(fabsf(cy), fabsf(cz))) + 1e-8f;
                float val  = (dist > 1.0f) ? (2.0f - 1.0f / dist) : dist;
                float s    = val * 0.5f / dist;
                cx *= s; cy *= s; cz *= s;
            }
            r = slow_sample(vol, cx, cy, cz);
        }
        __builtin_nontemporal_store(r, &out[i]);
    }
}

// ---- fallback tier: direct f32 if workspace too small ----
__global__ __launch_bounds__(256) void sample_f32_kernel(
    const fvec4* __restrict__ xyz,
    const float* __restrict__ vol,
    const float* __restrict__ aabb,
    const int* __restrict__ contract,
    float* __restrict__ out,
    int n)
{
    int i = blockIdx.x * blockDim.x + threadIdx.x;
    if (i >= n) return;

    const fvec4 p = xyz[i];
    const float amin_x = aabb[0], amin_y = aabb[1], amin_z = aabb[2];
    const float amax_x = aabb[3], amax_y = aabb[4], amax_z = aabb[5];

    float cx = (p.x - amin_x) * (2.0f / (amax_x - amin_x)) - 1.0f;
    float cy = (p.y - amin_y) * (2.0f / (amax_y - amin_y)) - 1.0f;
    float cz = (p.z - amin_z) * (2.0f / (amax_z - amin_z)) - 1.0f;

    if (*contract) {
        float dist = fmaxf(fabsf(cx), fmaxf(fabsf(cy), fabsf(cz))) + 1e-8f;
        float val  = (dist > 1.0f) ? (2.0f - 1.0f / dist) : dist;
        float s    = val * 0.5f / dist;
        cx *= s; cy *= s; cz *= s;
    }

    out[i] = slow_sample(vol, cx, cy, cz);
}

extern "C" void kernel_launch(void* const* d_in, const int* in_sizes, int n_in,
                              void* d_out, int out_size, void* d_ws, size_t ws_size,
                              hipStream_t stream) {
    const float*  xyz      = (const float*)d_in[0];
    const float*  vol      = (const float*)d_in[1];
    const float*  aabb     = (const float*)d_in[2];
    const int*    contract = (const int*)d_in[3];
    float*        out      = (float*)d_out;

    int n = in_sizes[0] / 4;
    int block = 256;

    if (ws_size >= QBYTES) {
        unsigned short* qt = (unsigned short*)d_ws;
        build_qt_kernel<<<(QENT + block - 1) / block, block, 0, stream>>>(vol, qt);
        int grid = (n + block * KPT - 1) / (block * KPT);
        sample_phase_kernel<<<grid, block, 0, stream>>>(
            xyz, qt, vol, aabb, contract, out, n, 0);
        sample_phase_kernel<<<grid, block, 0, stream>>>(
            xyz, qt, vol, aabb, contract, out, n, 1);
    } else {
        int grid_pts = (n + block - 1) / block;
        sample_f32_kernel<<<grid_pts, block, 0, stream>>>(
            (const fvec4*)xyz, vol, aabb, contract, out, n);
    }
}

// Round 5
// 351.683 us; speedup vs baseline: 1.2100x; 1.2100x over previous
//
#include <hip/hip_runtime.h>

// AlphaGridMask: normalize coords (+ inf-norm contract), trilinear sample of
// 256^3 volume (align_corners=True, zero pad).
//
// R10: two-phase u16-pair table + KPT=4 at HIGH occupancy.
// Evidence ladder:
//   R6:  KPT=1, 20 VGPR, occ 75%  -> 81 us/phase (latency-hiding = 24w x 2 misses)
//   R7:  KPT=4, 40 VGPR, occ 60%, but 8 transactions/pt -> transaction-bound
//   R8:  KPT=8 1-pass 33MB table -> not cache-resident (FETCH 522MB)
//   R9b: KPT=8, 104 VGPR, occ 20% -> 128 us/phase (occupancy collapse ate the MLP)
// Hiding capacity ~ occupancy x per-thread MLP. KPT=8 traded occupancy 4x down
// for MLP 8x up: net ~1x but longer serial chains -> slower. KPT=4 fits ~40-60
// VGPR (R7 proof) -> keeps ~24 waves/CU AND 4x the in-flight scattered loads.
// __launch_bounds__(256,6) caps VGPR at 85 to protect occupancy.
// Transactions stay at 2 aligned-ish dwords/pt (u16-pair table, R6 scheme).

#define DD 256
#define HH 256
#define WW 256

#define R0   47                       // min accessed corner index
#define XE   162                      // x entries: 47..208
#define YE   161                      // y-pair bases: 47..207 (pair = y,y+1)
#define ZE   162                      // z entries: 47..208
#define QENT (XE * YE * ZE)
#define QBYTES ((size_t)QENT * 2)     // 8,449,128 bytes

#define KPT 4                         // points per thread (MLP sweet spot)

typedef float fvec4 __attribute__((ext_vector_type(4)));
typedef unsigned int u32a2 __attribute__((aligned(2)));

__device__ __forceinline__ unsigned int quant_u8(float v) {
    return (unsigned int)(fminf(fmaxf(v, 0.f), 1.f) * 255.0f + 0.5f);
}

// QT[((z-47)*YE + (yb-47))*XE + (x-47)] = q(vol[z][yb][x]) | q(vol[z][yb+1][x])<<8
__global__ __launch_bounds__(256) void build_qt_kernel(
    const float* __restrict__ vol,
    unsigned short* __restrict__ qt)
{
    int i = blockIdx.x * blockDim.x + threadIdx.x;
    if (i >= QENT) return;
    int x  = i % XE;
    int t  = i / XE;
    int yb = t % YE;
    int z  = t / YE;
    size_t base = ((size_t)(z + R0) << 16) | ((yb + R0) << 8) | (x + R0);
    float v0 = __builtin_nontemporal_load(vol + base);
    float v1 = __builtin_nontemporal_load(vol + base + WW);   // y+1 row
    qt[i] = (unsigned short)(quant_u8(v0) | (quant_u8(v1) << 8));
}

// exact f32 trilinear with zero-padding masks (cold path / fallback)
__device__ __forceinline__ float slow_sample(const float* __restrict__ vol,
                                             float cx, float cy, float cz)
{
    float ix = (cx + 1.0f) * 0.5f * (float)(WW - 1);
    float iy = (cy + 1.0f) * 0.5f * (float)(HH - 1);
    float iz = (cz + 1.0f) * 0.5f * (float)(DD - 1);

    float x0f = floorf(ix), y0f = floorf(iy), z0f = floorf(iz);
    float tx = ix - x0f, ty = iy - y0f, tz = iz - z0f;
    int x0 = (int)x0f, y0 = (int)y0f, z0 = (int)z0f;
    int x1 = x0 + 1,   y1 = y0 + 1,   z1 = z0 + 1;

    float mx0 = ((unsigned)x0 < (unsigned)WW) ? 1.0f : 0.0f;
    float mx1 = ((unsigned)x1 < (unsigned)WW) ? 1.0f : 0.0f;
    float my0 = ((unsigned)y0 < (unsigned)HH) ? 1.0f : 0.0f;
    float my1 = ((unsigned)y1 < (unsigned)HH) ? 1.0f : 0.0f;
    float mz0 = ((unsigned)z0 < (unsigned)DD) ? 1.0f : 0.0f;
    float mz1 = ((unsigned)z1 < (unsigned)DD) ? 1.0f : 0.0f;

    int xc0 = min(max(x0, 0), WW - 1), xc1 = min(max(x1, 0), WW - 1);
    int yc0 = min(max(y0, 0), HH - 1), yc1 = min(max(y1, 0), HH - 1);
    int zc0 = min(max(z0, 0), DD - 1), zc1 = min(max(z1, 0), DD - 1);

    float wx0 = (1.0f - tx) * mx0, wx1 = tx * mx1;
    float wy0 = (1.0f - ty) * my0, wy1 = ty * my1;
    float wz0 = (1.0f - tz) * mz0, wz1 = tz * mz1;

    const float* vz0y0 = vol + (((size_t)zc0 * HH + yc0) * WW);
    const float* vz0y1 = vol + (((size_t)zc0 * HH + yc1) * WW);
    const float* vz1y0 = vol + (((size_t)zc1 * HH + yc0) * WW);
    const float* vz1y1 = vol + (((size_t)zc1 * HH + yc1) * WW);

    return wz0 * (wy0 * (wx0 * vz0y0[xc0] + wx1 * vz0y0[xc1]) +
                  wy1 * (wx0 * vz0y1[xc0] + wx1 * vz0y1[xc1])) +
           wz1 * (wy0 * (wx0 * vz1y0[xc0] + wx1 * vz1y0[xc1]) +
                  wy1 * (wx0 * vz1y1[xc0] + wx1 * vz1y1[xc1]));
}

// phase 0: inside points (dist<=1, and everything when contract==0); phase 1: shell
// ca[k] semantics: >=0 fast table index; -1 not-my-phase/oob-i; -2 my phase, slow path
__global__ __launch_bounds__(256, 6) void sample_phase_kernel(
    const float* __restrict__ xyz,            // [N*4]
    const unsigned short* __restrict__ qt,
    const float* __restrict__ vol,            // slow-path fallback only
    const float* __restrict__ aabb,
    const int* __restrict__ contract,
    float* __restrict__ out,
    int n, int phase)
{
    int i0 = blockIdx.x * (256 * KPT) + threadIdx.x;

    const float amin_x = aabb[0], amin_y = aabb[1], amin_z = aabb[2];
    const float amax_x = aabb[3], amax_y = aabb[4], amax_z = aabb[5];
    const float gx = 2.0f / (amax_x - amin_x);
    const float gy = 2.0f / (amax_y - amin_y);
    const float gz = 2.0f / (amax_z - amin_z);
    const int ct = *contract;

    // ---- stage 1: issue all K xyz loads (independent, NT, coalesced) ----
    fvec4 p[KPT];
    #pragma unroll
    for (int k = 0; k < KPT; k++) {
        int i = i0 + k * 256;
        if (i < n) p[k] = __builtin_nontemporal_load((const fvec4*)xyz + i);
        else       p[k] = (fvec4)(0.0f);
    }

    // ---- stage 2: coords -> phase mask, table index, lerp weights ----
    int   ca[KPT];
    float tx[KPT], ty[KPT], tz[KPT];
    #pragma unroll
    for (int k = 0; k < KPT; k++) {
        int i = i0 + k * 256;
        float cx = (p[k].x - amin_x) * gx - 1.0f;
        float cy = (p[k].y - amin_y) * gy - 1.0f;
        float cz = (p[k].z - amin_z) * gz - 1.0f;
        bool outside = false;
        if (ct) {
            float dist = fmaxf(fabsf(cx), fmaxf(fabsf(cy), fabsf(cz))) + 1e-8f;
            outside = (dist > 1.0f);
            float val  = outside ? (2.0f - 1.0f / dist) : dist;
            float s    = val * 0.5f / dist;
            cx *= s; cy *= s; cz *= s;
        }
        bool mine = (i < n) && (outside == (phase != 0));

        float ix = (cx + 1.0f) * 0.5f * (float)(WW - 1);
        float iy = (cy + 1.0f) * 0.5f * (float)(HH - 1);
        float iz = (cz + 1.0f) * 0.5f * (float)(DD - 1);
        float x0f = floorf(ix), y0f = floorf(iy), z0f = floorf(iz);
        tx[k] = ix - x0f; ty[k] = iy - y0f; tz[k] = iz - z0f;
        int x0 = (int)x0f, y0 = (int)y0f, z0 = (int)z0f;

        bool fast = ((unsigned)(x0 - R0) <= (unsigned)(XE - 2)) &
                    ((unsigned)(y0 - R0) <= (unsigned)(YE - 1)) &
                    ((unsigned)(z0 - R0) <= (unsigned)(ZE - 2));
        int idx = ((z0 - R0) * YE + (y0 - R0)) * XE + (x0 - R0);
        ca[k] = mine ? (fast ? idx : -2) : -1;
    }

    // ---- stage 3: issue all scattered table loads together (MLP) ----
    unsigned int L0[KPT], L1[KPT];
    #pragma unroll
    for (int k = 0; k < KPT; k++) {
        if (ca[k] >= 0) {
            L0[k] = *(const u32a2*)(qt + ca[k]);
            L1[k] = *(const u32a2*)(qt + ca[k] + YE * XE);
        } else {
            L0[k] = L1[k] = 0u;
        }
    }

    // ---- stage 4: trilinear combine + NT store ----
    #pragma unroll
    for (int k = 0; k < KPT; k++) {
        if (ca[k] == -1) continue;
        int i = i0 + k * 256;
        float r;
        if (__builtin_expect(ca[k] >= 0, 1)) {
            float v000 = (float)( L0[k]        & 0xFFu);
            float v010 = (float)((L0[k] >>  8) & 0xFFu);
            float v001 = (float)((L0[k] >> 16) & 0xFFu);
            float v011 = (float)( L0[k] >> 24);
            float v100 = (float)( L1[k]        & 0xFFu);
            float v110 = (float)((L1[k] >>  8) & 0xFFu);
            float v101 = (float)((L1[k] >> 16) & 0xFFu);
            float v111 = (float)( L1[k] >> 24);

            float wx0 = 1.0f - tx[k], wx1 = tx[k];
            float wy0 = 1.0f - ty[k], wy1 = ty[k];
            float wz0 = 1.0f - tz[k], wz1 = tz[k];

            r = (wz0 * (wy0 * (wx0 * v000 + wx1 * v001) +
                        wy1 * (wx0 * v010 + wx1 * v011)) +
                 wz1 * (wy0 * (wx0 * v100 + wx1 * v101) +
                        wy1 * (wx0 * v110 + wx1 * v111))) * (1.0f / 255.0f);
        } else {
            // cold path: recompute coords from a reload (keeps hot regs lean)
            fvec4 q = *((const fvec4*)xyz + i);
            float cx = (q.x - amin_x) * gx - 1.0f;
            float cy = (q.y - amin_y) * gy - 1.0f;
            float cz = (q.z - amin_z) * gz - 1.0f;
            if (ct) {
                float dist = fmaxf(fabsf(cx), fmaxf(fabsf(cy), fabsf(cz))) + 1e-8f;
                float val  = (dist > 1.0f) ? (2.0f - 1.0f / dist) : dist;
                float s    = val * 0.5f / dist;
                cx *= s; cy *= s; cz *= s;
            }
            r = slow_sample(vol, cx, cy, cz);
        }
        __builtin_nontemporal_store(r, &out[i]);
    }
}

// ---- fallback tier: direct f32 if workspace too small ----
__global__ __launch_bounds__(256) void sample_f32_kernel(
    const fvec4* __restrict__ xyz,
    const float* __restrict__ vol,
    const float* __restrict__ aabb,
    const int* __restrict__ contract,
    float* __restrict__ out,
    int n)
{
    int i = blockIdx.x * blockDim.x + threadIdx.x;
    if (i >= n) return;

    const fvec4 p = xyz[i];
    const float amin_x = aabb[0], amin_y = aabb[1], amin_z = aabb[2];
    const float amax_x = aabb[3], amax_y = aabb[4], amax_z = aabb[5];

    float cx = (p.x - amin_x) * (2.0f / (amax_x - amin_x)) - 1.0f;
    float cy = (p.y - amin_y) * (2.0f / (amax_y - amin_y)) - 1.0f;
    float cz = (p.z - amin_z) * (2.0f / (amax_z - amin_z)) - 1.0f;

    if (*contract) {
        float dist = fmaxf(fabsf(cx), fmaxf(fabsf(cy), fabsf(cz))) + 1e-8f;
        float val  = (dist > 1.0f) ? (2.0f - 1.0f / dist) : dist;
        float s    = val * 0.5f / dist;
        cx *= s; cy *= s; cz *= s;
    }

    out[i] = slow_sample(vol, cx, cy, cz);
}

extern "C" void kernel_launch(void* const* d_in, const int* in_sizes, int n_in,
                              void* d_out, int out_size, void* d_ws, size_t ws_size,
                              hipStream_t stream) {
    const float*  xyz      = (const float*)d_in[0];
    const float*  vol      = (const float*)d_in[1];
    const float*  aabb     = (const float*)d_in[2];
    const int*    contract = (const int*)d_in[3];
    float*        out      = (float*)d_out;

    int n = in_sizes[0] / 4;
    int block = 256;

    if (ws_size >= QBYTES) {
        unsigned short* qt = (unsigned short*)d_ws;
        build_qt_kernel<<<(QENT + block - 1) / block, block, 0, stream>>>(vol, qt);
        int grid = (n + block * KPT - 1) / (block * KPT);
        sample_phase_kernel<<<grid, block, 0, stream>>>(
            xyz, qt, vol, aabb, contract, out, n, 0);
        sample_phase_kernel<<<grid, block, 0, stream>>>(
            xyz, qt, vol, aabb, contract, out, n, 1);
    } else {
        int grid_pts = (n + block - 1) / block;
        sample_f32_kernel<<<grid_pts, block, 0, stream>>>(
            (const fvec4*)xyz, vol, aabb, contract, out, n);
    }
}